// Round 1
// baseline (3940.966 us; speedup 1.0000x reference)
//
#include <hip/hip_runtime.h>

#define NDIM 2
#define NCELLS 200
#define BATCH 128
#define NPTS (BATCH * NCELLS)
#define XROW (2 + NCELLS * NDIM + 5) /* 407 */
#define DT_F 0.001f

__device__ __forceinline__ float softplus_f(float z) {
    // stable softplus: max(z,0) + log1p(exp(-|z|))
    float e = __expf(-fabsf(z));
    return fmaxf(z, 0.0f) + __logf(1.0f + e);
}

__global__ void __launch_bounds__(64, 1) phinn_kernel(
    const float* __restrict__ w0, const float* __restrict__ b0,
    const float* __restrict__ w1, const float* __restrict__ b1,
    const float* __restrict__ w2, const float* __restrict__ b2,
    const float* __restrict__ w3, const float* __restrict__ b3,
    const float* __restrict__ w4, const float* __restrict__ b4,
    const float* __restrict__ wt, const float* __restrict__ x,
    float* __restrict__ out)
{
    const int tid = blockIdx.x * 64 + threadIdx.x;
    if (tid >= NPTS) return;
    const int bi = tid / NCELLS;
    const int ci = tid - bi * NCELLS;
    const float* xr = x + bi * XROW;

    float y0 = xr[2 + ci * 2 + 0];
    float y1 = xr[2 + ci * 2 + 1];
    float ts = xr[0];
    const float sp0    = xr[XROW - 5];
    const float sg_lo0 = xr[XROW - 4], sg_lo1 = xr[XROW - 3];
    const float sg_hi0 = xr[XROW - 2], sg_hi1 = xr[XROW - 1];

    const float wt00 = wt[0], wt01 = wt[1], wt10 = wt[2], wt11 = wt[3];

    // nsteps from x[0,0], x[0,1]  (round((t1-t0)/dt))
    const float gt0 = x[0], gt1 = x[1];
    const int nsteps = (int)((gt1 - gt0) / DT_F + 0.5f);

    #pragma unroll 1
    for (int it = 0; it < nsteps; ++it) {
        const bool lo = ts < sp0;
        const float sv0 = lo ? sg_lo0 : sg_hi0;
        const float sv1 = lo ? sg_lo1 : sg_hi1;
        const float tilt0 = sv0 * wt00 + sv1 * wt01;
        const float tilt1 = sv0 * wt10 + sv1 * wt11;

        // ---------------- forward ----------------
        float a1[16];
        #pragma unroll
        for (int j = 0; j < 16; ++j) {
            float z = b0[j];
            z = fmaf(w0[2 * j + 0], y0, z);
            z = fmaf(w0[2 * j + 1], y1, z);
            a1[j] = softplus_f(z);
        }
        float a2[32];
        #pragma unroll
        for (int j = 0; j < 32; ++j) {
            float z = b1[j];
            #pragma unroll
            for (int k = 0; k < 16; ++k) z = fmaf(w1[16 * j + k], a1[k], z);
            a2[j] = softplus_f(z);
        }
        float a3[32];
        #pragma unroll
        for (int j = 0; j < 32; ++j) {
            float z = b2[j];
            #pragma unroll
            for (int k = 0; k < 32; ++k) z = fmaf(w2[32 * j + k], a2[k], z);
            a3[j] = softplus_f(z);
        }
        float a4[16];
        #pragma unroll
        for (int j = 0; j < 16; ++j) {
            float z = b3[j];
            #pragma unroll
            for (int k = 0; k < 32; ++k) z = fmaf(w3[32 * j + k], a3[k], z);
            a4[j] = softplus_f(z);
        }

        // ---------------- backward (grad wrt y) ----------------
        // sigma(z) = 1 - exp(-softplus(z)) = 1 - exp(-a)   (exact identity)
        float g4[16];
        #pragma unroll
        for (int j = 0; j < 16; ++j)
            g4[j] = w4[j] * (1.0f - __expf(-a4[j]));

        float g3[32];
        #pragma unroll
        for (int k = 0; k < 32; ++k) {
            float s = 0.0f;
            #pragma unroll
            for (int j = 0; j < 16; ++j) s = fmaf(w3[32 * j + k], g4[j], s);
            g3[k] = s * (1.0f - __expf(-a3[k]));
        }
        float g2[32];
        #pragma unroll
        for (int k = 0; k < 32; ++k) {
            float s = 0.0f;
            #pragma unroll
            for (int j = 0; j < 32; ++j) s = fmaf(w2[32 * j + k], g3[j], s);
            g2[k] = s * (1.0f - __expf(-a2[k]));
        }
        float g1[16];
        #pragma unroll
        for (int k = 0; k < 16; ++k) {
            float s = 0.0f;
            #pragma unroll
            for (int j = 0; j < 32; ++j) s = fmaf(w1[16 * j + k], g2[j], s);
            g1[k] = s * (1.0f - __expf(-a1[k]));
        }
        float gy0 = 0.0f, gy1 = 0.0f;
        #pragma unroll
        for (int j = 0; j < 16; ++j) {
            gy0 = fmaf(w0[2 * j + 0], g1[j], gy0);
            gy1 = fmaf(w0[2 * j + 1], g1[j], gy1);
        }

        y0 = fmaf(-(gy0 + tilt0), DT_F, y0);
        y1 = fmaf(-(gy1 + tilt1), DT_F, y1);
        ts += DT_F;
    }

    out[2 * tid + 0] = y0;
    out[2 * tid + 1] = y1;
}

extern "C" void kernel_launch(void* const* d_in, const int* in_sizes, int n_in,
                              void* d_out, int out_size, void* d_ws, size_t ws_size,
                              hipStream_t stream) {
    (void)in_sizes; (void)n_in; (void)d_ws; (void)ws_size; (void)out_size;
    const float* w0 = (const float*)d_in[0];
    const float* b0 = (const float*)d_in[1];
    const float* w1 = (const float*)d_in[2];
    const float* b1 = (const float*)d_in[3];
    const float* w2 = (const float*)d_in[4];
    const float* b2 = (const float*)d_in[5];
    const float* w3 = (const float*)d_in[6];
    const float* b3 = (const float*)d_in[7];
    const float* w4 = (const float*)d_in[8];
    const float* b4 = (const float*)d_in[9];
    const float* wt = (const float*)d_in[10];
    const float* x  = (const float*)d_in[11];
    float* out = (float*)d_out;

    dim3 grid((NPTS + 63) / 64), block(64);
    hipLaunchKernelGGL(phinn_kernel, grid, block, 0, stream,
                       w0, b0, w1, b1, w2, b2, w3, b3, w4, b4, wt, x, out);
}